// Round 4
// baseline (193.944 us; speedup 1.0000x reference)
//
#include <hip/hip_runtime.h>
#include <math.h>

#define NPX 4096          // 64*64 low-res pixels per batch
#define H2 128
#define W2 128

// K1: 1x1 conv (256->64) + BN + ReLU. grid (128 px-chunks, 2 co-halves), block 512.
// Block = 8 waves = 4 ci-quarters x 2 co-groups(16 co). lane = px. Weights via
// wave-uniform global reads -> compiler scalarizes to s_load (SGPR operand in FMA).
// ci-quarter partials reduced through LDS; BN+ReLU in epilogue. X read 2x total.
__global__ __launch_bounds__(512) void k1_conv1x1(
    const float* __restrict__ X, const float* __restrict__ w,
    const float* __restrict__ g, const float* __restrict__ bt,
    const float* __restrict__ m, const float* __restrict__ var,
    float* __restrict__ mid)
{
    __shared__ float red[8 * 16 * 64];   // [wave][j][lane] 32 KB
    int tid = threadIdx.x;
    int lane = tid & 63;
    int wv = __builtin_amdgcn_readfirstlane(tid >> 6);   // 0..7
    int ciq = wv >> 1, cogl = wv & 1;
    int p = blockIdx.x * 64 + lane;
    int bb = p >> 12, sp = p & (NPX - 1);
    int co0 = blockIdx.y * 32 + cogl * 16;
    int ci0 = ciq * 64;

    const float* xp = X + ((size_t)bb * 256 + ci0) * NPX + sp;
    const float* wp = w + (size_t)co0 * 256 + ci0;   // wave-uniform -> s_load

    float acc[16];
    #pragma unroll
    for (int j = 0; j < 16; ++j) acc[j] = 0.f;

    #pragma unroll 4
    for (int ci = 0; ci < 64; ++ci) {
        float x = xp[(size_t)ci * NPX];
        #pragma unroll
        for (int j = 0; j < 16; ++j)
            acc[j] += x * wp[j * 256 + ci];
    }

    #pragma unroll
    for (int j = 0; j < 16; ++j)
        red[(wv * 16 + j) * 64 + lane] = acc[j];
    __syncthreads();

    for (int t2 = tid; t2 < 2048; t2 += 512) {
        int j = t2 >> 6;            // 0..31 local co
        int pxl = t2 & 63;
        int cg = j >> 4, jj = j & 15;
        float s = 0.f;
        #pragma unroll
        for (int q = 0; q < 4; ++q)
            s += red[((q * 2 + cg) * 16 + jj) * 64 + pxl];
        int co = blockIdx.y * 32 + j;
        float inv = g[co] * rsqrtf(var[co] + 1e-5f);
        float a = fmaxf(s * inv + (bt[co] - m[co] * inv), 0.f);
        int p2 = blockIdx.x * 64 + pxl;
        mid[((size_t)(p2 >> 12) * 64 + co) * NPX + (p2 & (NPX - 1))] = a;
    }
}

// K2a: 3x3 conv (64->100) on pre-activated mid. grid (25 co-quads, 16 tiles x 2 b),
// block 256 = 16x16 px, thread = 1 px x 4 co. Weights: wave-uniform global reads
// -> s_load (no LDS). Patch tile pitch 24: wave rows hit banks {0,24,16,8} ->
// exact 2-way everywhere = conflict-free.
__global__ __launch_bounds__(256) void k2a_conv3x3(
    const float* __restrict__ mid, const float* __restrict__ ew,
    float* __restrict__ enc)
{
    __shared__ float mt[16 * 432];   // 16 ci x 18 rows x pitch 24 = 27.6 KB

    int tid = threadIdx.x;
    int cq = blockIdx.x;             // co = 4*cq + j
    int t = blockIdx.y;
    int bb = t >> 4;
    int tile = t & 15;
    int ty0 = (tile >> 2) * 16, tx0 = (tile & 3) * 16;
    int qy = tid >> 4, qx = tid & 15;

    const float* wbase = ew + (size_t)(4 * cq) * 64 * 9;   // [j][ci][k], uniform

    float acc[4] = {0.f, 0.f, 0.f, 0.f};

    for (int cc = 0; cc < 4; ++cc) {
        __syncthreads();
        for (int idx = tid; idx < 6912; idx += 256) {   // 16 ci x 18 x 24
            int ci = idx / 432;
            int rem = idx - ci * 432;
            int r = rem / 24, c = rem - r * 24;
            int gy = ty0 + r - 1, gx = tx0 + c - 1;
            float v = 0.f;
            if (c < 18 && (unsigned)gy < 64u && (unsigned)gx < 64u)
                v = mid[((size_t)bb * 64 + cc * 16 + ci) * NPX + gy * 64 + gx];
            mt[idx] = v;
        }
        __syncthreads();

        #pragma unroll 2
        for (int ci = 0; ci < 16; ++ci) {
            int base = ci * 432 + qy * 24 + qx;
            float nb[9];
            #pragma unroll
            for (int dy = 0; dy < 3; ++dy)
                #pragma unroll
                for (int dx = 0; dx < 3; ++dx)
                    nb[dy * 3 + dx] = mt[base + dy * 24 + dx];
            const float* wp = wbase + (cc * 16 + ci) * 9;   // uniform -> s_load
            #pragma unroll
            for (int j = 0; j < 4; ++j)
                #pragma unroll
                for (int k = 0; k < 9; ++k)
                    acc[j] += nb[k] * wp[j * 576 + k];
        }
    }

    int sp = (ty0 + qy) * 64 + tx0 + qx;
    #pragma unroll
    for (int j = 0; j < 4; ++j)
        enc[((size_t)bb * 100 + 4 * cq + j) * NPX + sp] = acc[j];
}

// K2b: BN + clamp + pow + softmax over 25 taps. wn layout [b][s*25+k][px].
__global__ __launch_bounds__(64) void k2b_softmax(
    const float* __restrict__ enc,
    const float* __restrict__ g, const float* __restrict__ bt,
    const float* __restrict__ m, const float* __restrict__ var,
    const float* __restrict__ power_p,
    float* __restrict__ wn)
{
    int s = blockIdx.x & 3;
    int p = (blockIdx.x >> 2) * 64 + threadIdx.x;
    int bb = p >> 12, sp = p & (NPX - 1);
    float pw = fmaxf(power_p[0], 1e-5f);
    float tv[25];
    float mx = -1e30f;
    #pragma unroll
    for (int k = 0; k < 25; ++k) {
        int co = 4 * k + s;
        float inv = g[co] * rsqrtf(var[co] + 1e-5f);
        float e = enc[((size_t)bb * 100 + co) * NPX + sp] * inv + (bt[co] - m[co] * inv);
        e = fmaxf(e, 1e-5f);
        float x = exp2f(pw * log2f(e));
        tv[k] = x;
        mx = fmaxf(mx, x);
    }
    float sum = 0.f;
    #pragma unroll
    for (int k = 0; k < 25; ++k) {
        float e = expf(tv[k] - mx);
        tv[k] = e;
        sum += e;
    }
    float r = 1.0f / sum;
    #pragma unroll
    for (int k = 0; k < 25; ++k)
        wn[((size_t)bb * 100 + s * 25 + k) * NPX + sp] = tv[k] * r;
}

// K3: reassembly. grid (2b x 16 tiles, 16 ch-chunks), block 256 = 16x16 low-res px.
// xt pitch 24 -> conflict-free 2-way LDS reads.
__global__ __launch_bounds__(256, 2) void k3_carafe(
    const float* __restrict__ X, const float* __restrict__ wn,
    float* __restrict__ out)
{
    __shared__ float xt[16 * 480];   // 16 ch x 20 rows x pitch 24 = 30.7 KB
    int tid = threadIdx.x;
    int bx = blockIdx.x;
    int bb = bx >> 4;
    int t = bx & 15;
    int ty0 = (t >> 2) * 16, tx0 = (t & 3) * 16;
    int c0 = blockIdx.y * 16;
    for (int idx = tid; idx < 7680; idx += 256) {   // 16 ch x 20 x 24
        int ch = idx / 480;
        int rem = idx - ch * 480;
        int r = rem / 24, cc = rem - r * 24;
        int gy = ty0 + r - 2, gx = tx0 + cc - 2;
        float val = 0.f;
        if (cc < 20 && (unsigned)gy < 64u && (unsigned)gx < 64u)
            val = X[((size_t)bb * 256 + c0 + ch) * NPX + gy * 64 + gx];
        xt[idx] = val;
    }
    int ylq = tid >> 4, xlq = tid & 15;
    int yl = ty0 + ylq, xl = tx0 + xlq;
    int px = yl * 64 + xl;
    float wv[100];
    #pragma unroll
    for (int j = 0; j < 100; ++j)
        wv[j] = wn[((size_t)bb * 100 + j) * NPX + px];
    __syncthreads();
    for (int ch = 0; ch < 16; ++ch) {
        float x[25];
        #pragma unroll
        for (int ki = 0; ki < 5; ++ki)
            #pragma unroll
            for (int kj = 0; kj < 5; ++kj)
                x[ki * 5 + kj] = xt[ch * 480 + (ylq + ki) * 24 + (xlq + kj)];
        float a0 = 0.f, a1 = 0.f, a2 = 0.f, a3 = 0.f;
        #pragma unroll
        for (int k = 0; k < 25; ++k) {
            a0 += wv[k]      * x[k];
            a1 += wv[25 + k] * x[k];
            a2 += wv[50 + k] * x[k];
            a3 += wv[75 + k] * x[k];
        }
        float* ob = out + ((size_t)(bb * 256 + c0 + ch) * H2 + 2 * yl) * W2 + 2 * xl;
        *(float2*)ob        = make_float2(a0, a1);
        *(float2*)(ob + W2) = make_float2(a2, a3);
    }
}

extern "C" void kernel_launch(void* const* d_in, const int* in_sizes, int n_in,
                              void* d_out, int out_size, void* d_ws, size_t ws_size,
                              hipStream_t stream)
{
    const float* X  = (const float*)d_in[0];
    const float* cw = (const float*)d_in[1];
    const float* cg = (const float*)d_in[2];
    const float* cb = (const float*)d_in[3];
    const float* cm = (const float*)d_in[4];
    const float* cv = (const float*)d_in[5];
    const float* ew = (const float*)d_in[6];
    const float* eg = (const float*)d_in[7];
    const float* eb = (const float*)d_in[8];
    const float* em = (const float*)d_in[9];
    const float* ev = (const float*)d_in[10];
    const float* pp = (const float*)d_in[11];
    float* out = (float*)d_out;

    float* ws  = (float*)d_ws;
    float* mid = ws;                        // 2*64*4096   floats (BN+ReLU applied)
    float* enc = ws + 524288;               // 2*100*4096  floats (raw conv sums)
    float* wn  = ws + 524288 + 819200;      // 2*100*4096  floats

    k1_conv1x1<<<dim3(128, 2), 512, 0, stream>>>(X, cw, cg, cb, cm, cv, mid);
    k2a_conv3x3<<<dim3(25, 32), 256, 0, stream>>>(mid, ew, enc);
    k2b_softmax<<<dim3(512), 64, 0, stream>>>(enc, eg, eb, em, ev, pp, wn);
    k3_carafe<<<dim3(32, 16), 256, 0, stream>>>(X, wn, out);
}